// Round 1
// baseline (1457.777 us; speedup 1.0000x reference)
//
#include <hip/hip_runtime.h>

#define DIM    20
#define NN     200000
#define EE     6400000
#define ITERS  3
#define BLOCK  256

// ---------------- CSR build kernels ----------------

__global__ void hist_kernel(const int* __restrict__ dst, int* __restrict__ deg, int E) {
    int e = blockIdx.x * BLOCK + threadIdx.x;
    if (e < E) atomicAdd(&deg[dst[e]], 1);
}

// Per-wave exclusive-scan segment allocation: one atomic per wave on the global
// cursor, so segments are NOT in node order — each node just records its own
// start in ptr[] (and cursor[] as the scatter write head).
__global__ void alloc_kernel(const int* __restrict__ deg, int* __restrict__ ptr,
                             int* __restrict__ cursor, int* __restrict__ counter, int n) {
    int u    = blockIdx.x * BLOCK + threadIdx.x;
    int lane = threadIdx.x & 63;
    int w    = (u < n) ? deg[u] : 0;
    int incl = w;
    #pragma unroll
    for (int off = 1; off < 64; off <<= 1) {
        int t = __shfl_up(incl, off, 64);
        if (lane >= off) incl += t;
    }
    int tot  = __shfl(incl, 63, 64);
    int base = 0;
    if (lane == 0) base = atomicAdd(counter, tot);
    base = __shfl(base, 0, 64);
    if (u < n) {
        int p = base + incl - w;
        ptr[u]    = p;
        cursor[u] = p;
    }
}

__global__ void scatter_kernel(const int* __restrict__ src, const int* __restrict__ dst,
                               int* __restrict__ cursor, int* __restrict__ ssrc, int E) {
    int e = blockIdx.x * BLOCK + threadIdx.x;
    if (e < E) {
        int d   = dst[e];
        int pos = atomicAdd(&cursor[d], 1);
        ssrc[pos] = src[e];
    }
}

// ---------------- fused GRU iteration ----------------

__device__ __forceinline__ void load_row20(float* a, const float* row) {
    const float4* v = (const float4*)row;
    float4 a0 = v[0], a1 = v[1], a2 = v[2], a3 = v[3], a4 = v[4];
    a[0]=a0.x; a[1]=a0.y; a[2]=a0.z; a[3]=a0.w;
    a[4]=a1.x; a[5]=a1.y; a[6]=a1.z; a[7]=a1.w;
    a[8]=a2.x; a[9]=a2.y; a[10]=a2.z; a[11]=a2.w;
    a[12]=a3.x; a[13]=a3.y; a[14]=a3.z; a[15]=a3.w;
    a[16]=a4.x; a[17]=a4.y; a[18]=a4.z; a[19]=a4.w;
}

__device__ __forceinline__ void acc_row20(float* x, const float* row) {
    const float4* v = (const float4*)row;
    float4 a0 = v[0], a1 = v[1], a2 = v[2], a3 = v[3], a4 = v[4];
    x[0]+=a0.x; x[1]+=a0.y; x[2]+=a0.z; x[3]+=a0.w;
    x[4]+=a1.x; x[5]+=a1.y; x[6]+=a1.z; x[7]+=a1.w;
    x[8]+=a2.x; x[9]+=a2.y; x[10]+=a2.z; x[11]+=a2.w;
    x[12]+=a3.x; x[13]+=a3.y; x[14]+=a3.z; x[15]+=a3.w;
    x[16]+=a4.x; x[17]+=a4.y; x[18]+=a4.z; x[19]+=a4.w;
}

__device__ __forceinline__ void store_row20(float* row, const float* o) {
    float4* v = (float4*)row;
    v[0] = make_float4(o[0],  o[1],  o[2],  o[3]);
    v[1] = make_float4(o[4],  o[5],  o[6],  o[7]);
    v[2] = make_float4(o[8],  o[9],  o[10], o[11]);
    v[3] = make_float4(o[12], o[13], o[14], o[15]);
    v[4] = make_float4(o[16], o[17], o[18], o[19]);
}

__device__ __forceinline__ float fast_sigmoid(float t) {
    return 1.0f / (1.0f + __expf(-t));
}

__device__ __forceinline__ float fast_tanh(float t) {
    t = fminf(fmaxf(t, -15.0f), 15.0f);
    float e2 = __expf(2.0f * t);
    return (e2 - 1.0f) / (e2 + 1.0f);
}

__global__ __launch_bounds__(BLOCK) void gru_kernel(
    const float* __restrict__ h_in, float* __restrict__ h_out,
    const int* __restrict__ depth, const int* __restrict__ ptr,
    const int* __restrict__ deg, const int* __restrict__ ssrc,
    const float* __restrict__ Wz, const float* __restrict__ bWz,
    const float* __restrict__ Uz, const float* __restrict__ bUz,
    const float* __restrict__ Wr, const float* __restrict__ bWr,
    const float* __restrict__ Ur, const float* __restrict__ bUr,
    const float* __restrict__ Wh, const float* __restrict__ bWh,
    const float* __restrict__ Uh, const float* __restrict__ bUh,
    int it, int isFinal)
{
    int u = blockIdx.x * BLOCK + threadIdx.x;
    if (u >= NN) return;

    int  dep = depth[u];
    bool act = (dep + it) <= ITERS;
    if (!act) {
        float4* o = (float4*)(h_out + (size_t)u * DIM);
        if (isFinal) {
            float4 z4 = make_float4(0.f, 0.f, 0.f, 0.f);
            #pragma unroll
            for (int q = 0; q < 5; ++q) o[q] = z4;
        } else {
            const float4* hi = (const float4*)(h_in + (size_t)u * DIM);
            #pragma unroll
            for (int q = 0; q < 5; ++q) o[q] = hi[q];
        }
        return;
    }

    // gather x = sum over active in-neighbors of h_in[v]
    float x[DIM];
    #pragma unroll
    for (int k = 0; k < DIM; ++k) x[k] = 0.0f;
    int p = ptr[u], d = deg[u];
    for (int e = 0; e < d; ++e) {
        int v = ssrc[p + e];
        if (depth[v] + it <= ITERS) {
            acc_row20(x, h_in + (size_t)v * DIM);
        }
    }

    float h[DIM];
    load_row20(h, h_in + (size_t)u * DIM);

    // z and r gates (weights are wave-uniform -> scalar loads)
    float z[DIM], rh[DIM];
    #pragma unroll
    for (int j = 0; j < DIM; ++j) {
        float sz = bWz[j] + bUz[j];
        float sr = bWr[j] + bUr[j];
        #pragma unroll
        for (int k = 0; k < DIM; ++k) {
            sz += x[k] * Wz[j * DIM + k];
            sz += h[k] * Uz[j * DIM + k];
            sr += x[k] * Wr[j * DIM + k];
            sr += h[k] * Ur[j * DIM + k];
        }
        z[j]  = fast_sigmoid(sz);
        rh[j] = fast_sigmoid(sr) * h[j];   // r[j]*h[j]
    }

    // candidate + output
    float o[DIM];
    #pragma unroll
    for (int j = 0; j < DIM; ++j) {
        float sh = bWh[j] + bUh[j];
        #pragma unroll
        for (int k = 0; k < DIM; ++k) {
            sh += x[k]  * Wh[j * DIM + k];
            sh += rh[k] * Uh[j * DIM + k];
        }
        float hc = fast_tanh(sh);
        o[j] = z[j] * h[j] + (1.0f - z[j]) * hc;
    }

    store_row20(h_out + (size_t)u * DIM, o);
}

// ---------------- launch ----------------

extern "C" void kernel_launch(void* const* d_in, const int* in_sizes, int n_in,
                              void* d_out, int out_size, void* d_ws, size_t ws_size,
                              hipStream_t stream) {
    const float* h0    = (const float*)d_in[0];
    const int*   depth = (const int*)d_in[1];
    const int*   esrc  = (const int*)d_in[2];
    const int*   edst  = (const int*)d_in[3];
    const float* Wz  = (const float*)d_in[4];  const float* bWz = (const float*)d_in[5];
    const float* Uz  = (const float*)d_in[6];  const float* bUz = (const float*)d_in[7];
    const float* Wr  = (const float*)d_in[8];  const float* bWr = (const float*)d_in[9];
    const float* Ur  = (const float*)d_in[10]; const float* bUr = (const float*)d_in[11];
    const float* Wh  = (const float*)d_in[12]; const float* bWh = (const float*)d_in[13];
    const float* Uh  = (const float*)d_in[14]; const float* bUh = (const float*)d_in[15];
    float* out = (float*)d_out;

    char* ws = (char*)d_ws;
    // layout: deg[N] | counter(+pad 64) | ptr[N] | cursor[N] | ssrc[E] | h1[N*DIM] | h2[N*DIM]
    int*   deg     = (int*)ws;
    int*   counter = (int*)(ws + (size_t)NN * 4);
    int*   ptr     = (int*)(ws + (size_t)(NN + 64) * 4);
    int*   cursor  = (int*)(ws + (size_t)(2 * NN + 64) * 4);
    int*   ssrc    = (int*)(ws + (size_t)(3 * NN + 64) * 4);
    float* h1      = (float*)(ws + (size_t)(3 * NN + 64) * 4 + (size_t)EE * 4);
    float* h2      = h1 + (size_t)NN * DIM;

    // zero deg + counter (ws is poisoned 0xAA before every launch)
    hipMemsetAsync(deg, 0, (size_t)(NN + 64) * 4, stream);

    int egrid = (EE + BLOCK - 1) / BLOCK;
    int ngrid = (NN + BLOCK - 1) / BLOCK;

    hist_kernel   <<<egrid, BLOCK, 0, stream>>>(edst, deg, EE);
    alloc_kernel  <<<ngrid, BLOCK, 0, stream>>>(deg, ptr, cursor, counter, NN);
    scatter_kernel<<<egrid, BLOCK, 0, stream>>>(esrc, edst, cursor, ssrc, EE);

    gru_kernel<<<ngrid, BLOCK, 0, stream>>>(h0, h1, depth, ptr, deg, ssrc,
        Wz, bWz, Uz, bUz, Wr, bWr, Ur, bUr, Wh, bWh, Uh, bUh, 0, 0);
    gru_kernel<<<ngrid, BLOCK, 0, stream>>>(h1, h2, depth, ptr, deg, ssrc,
        Wz, bWz, Uz, bUz, Wr, bWr, Ur, bUr, Wh, bWh, Uh, bUh, 1, 0);
    gru_kernel<<<ngrid, BLOCK, 0, stream>>>(h2, out, depth, ptr, deg, ssrc,
        Wz, bWz, Uz, bUz, Wr, bWr, Ur, bUr, Wh, bWh, Uh, bUh, 2, 1);
}

// Round 2
// 645.524 us; speedup vs baseline: 2.2583x; 2.2583x over previous
//
#include <hip/hip_runtime.h>

#define DIM    20
#define NN     200000
#define EE     6400000
#define ITERS  3
#define BLOCK  256

// Bucketing geometry
#define NODES_PER_FINE   64
#define NFINE            3125        // 200000/64 exactly
#define NODES_PER_COARSE 2048
#define NCOARSE          98          // ceil(200000/2048)
#define FINE_PER_COARSE  32
#define TILE             4096        // edges per block tile in P1/P2
#define IPT              16          // items per thread (TILE/BLOCK)

typedef unsigned int u32;

// ---------------- K1: fine-bucket histogram (LDS-binned) ----------------
__global__ __launch_bounds__(BLOCK) void k1_count(const int* __restrict__ edst,
                                                  int* __restrict__ fine_cnt) {
    __shared__ u32 lhist[NFINE];
    int tid = threadIdx.x;
    for (int i = tid; i < NFINE; i += BLOCK) lhist[i] = 0;
    __syncthreads();
    for (int e = blockIdx.x * BLOCK + tid; e < EE; e += gridDim.x * BLOCK) {
        int d = edst[e];
        atomicAdd(&lhist[d >> 6], 1u);
    }
    __syncthreads();
    for (int i = tid; i < NFINE; i += BLOCK) {
        u32 v = lhist[i];
        if (v) atomicAdd((u32*)&fine_cnt[i], v);
    }
}

// ---------------- K2: scan fine counts -> bases/cursors ----------------
__global__ __launch_bounds__(BLOCK) void k2_scan(const int* __restrict__ fine_cnt,
                                                 int* __restrict__ fine_base,
                                                 int* __restrict__ fine_cursor,
                                                 int* __restrict__ coarse_base,
                                                 int* __restrict__ coarse_cursor,
                                                 int* __restrict__ ptr) {
    const int CH = 13;                       // 256*13 = 3328 >= 3125
    int tid = threadIdx.x;
    int loc[CH];
    int base = tid * CH;
    int s = 0;
    #pragma unroll
    for (int j = 0; j < CH; ++j) {
        int idx = base + j;
        int v = (idx < NFINE) ? fine_cnt[idx] : 0;
        loc[j] = v; s += v;
    }
    // block exclusive scan of s over 256 threads
    __shared__ int wsum[4];
    int lane = tid & 63, wid = tid >> 6;
    int incl = s;
    #pragma unroll
    for (int off = 1; off < 64; off <<= 1) {
        int t = __shfl_up(incl, off, 64);
        if (lane >= off) incl += t;
    }
    if (lane == 63) wsum[wid] = incl;
    __syncthreads();
    int woff = 0;
    for (int w = 0; w < wid; ++w) woff += wsum[w];
    int run = woff + incl - s;               // exclusive prefix for this thread
    #pragma unroll
    for (int j = 0; j < CH; ++j) {
        int idx = base + j;
        if (idx < NFINE) {
            fine_base[idx]   = run;
            fine_cursor[idx] = run;
            run += loc[j];
        }
    }
    if (tid == 0) { fine_base[NFINE] = EE; ptr[NN] = EE; }
    __syncthreads();
    if (tid < NCOARSE + 1) {
        int f = tid * FINE_PER_COARSE; if (f > NFINE) f = NFINE;
        int v = fine_base[f];
        coarse_base[tid] = v;
        if (tid < NCOARSE) coarse_cursor[tid] = v;
    }
}

// ---------------- P1: split edges into 98 coarse buckets ----------------
// item u32 = dlow(11) | src<<11 (18) | dep<<29 (3)
__global__ __launch_bounds__(BLOCK) void p1_split(const int* __restrict__ esrc,
                                                  const int* __restrict__ edst,
                                                  const int* __restrict__ depth,
                                                  int* __restrict__ coarse_cursor,
                                                  u32* __restrict__ buf1) {
    __shared__ u32 lhist[NCOARSE];
    __shared__ u32 gbase[NCOARSE];
    int tid = threadIdx.x;
    int start = blockIdx.x * TILE;
    if (tid < NCOARSE) lhist[tid] = 0;
    __syncthreads();

    u32 item[IPT]; u32 key[IPT]; u32 rank[IPT];
    #pragma unroll
    for (int k = 0; k < IPT; ++k) {
        int e = start + k * BLOCK + tid;
        if (e < EE) {
            int d = edst[e];
            int s = esrc[e];
            u32 dep = (u32)depth[s];
            u32 c = (u32)d >> 11;
            key[k]  = c;
            item[k] = ((u32)d & 2047u) | ((u32)s << 11) | (dep << 29);
            rank[k] = atomicAdd(&lhist[c], 1u);
        }
    }
    __syncthreads();
    if (tid < NCOARSE) {
        u32 cnt = lhist[tid];
        gbase[tid] = cnt ? (u32)atomicAdd((u32*)&coarse_cursor[tid], cnt) : 0u;
    }
    __syncthreads();
    #pragma unroll
    for (int k = 0; k < IPT; ++k) {
        int e = start + k * BLOCK + tid;
        if (e < EE) buf1[gbase[key[k]] + rank[k]] = item[k];
    }
}

// ---------------- P2: split coarse buckets into fine (64-node) buckets ----------------
// item u32 = ln(6) | src<<6 (18) | dep<<24 (3)
__global__ __launch_bounds__(BLOCK) void p2_split(const u32* __restrict__ buf1,
                                                  const int* __restrict__ coarse_base,
                                                  int* __restrict__ fine_cursor,
                                                  u32* __restrict__ buf2) {
    __shared__ u32 lhist[2 * FINE_PER_COARSE];
    __shared__ u32 gbase[2 * FINE_PER_COARSE];
    __shared__ int cb[NCOARSE + 1];
    __shared__ int sc0;
    int tid = threadIdx.x;
    int start = blockIdx.x * TILE;
    if (tid < NCOARSE + 1) cb[tid] = coarse_base[tid];
    if (tid < 2 * FINE_PER_COARSE) { lhist[tid] = 0; gbase[tid] = 0; }
    __syncthreads();
    if (tid == 0) {
        int c = 0;
        while (c + 1 < NCOARSE && cb[c + 1] <= start) ++c;
        sc0 = c;
    }
    __syncthreads();
    int c0 = sc0;
    int b1 = cb[c0 + 1];                      // boundary between coarse c0 and c0+1

    u32 item[IPT]; u32 key[IPT]; u32 rank[IPT];
    #pragma unroll
    for (int k = 0; k < IPT; ++k) {
        int i = start + k * BLOCK + tid;
        if (i < EE) {
            u32 w = buf1[i];
            u32 dlow = w & 2047u;
            u32 sdep = w >> 11;               // src(18) | dep<<18
            u32 kk = ((i < b1) ? 0u : (u32)FINE_PER_COARSE) + (dlow >> 6);
            key[k]  = kk;
            item[k] = (dlow & 63u) | (sdep << 6);
            rank[k] = atomicAdd(&lhist[kk], 1u);
        }
    }
    __syncthreads();
    if (tid < 2 * FINE_PER_COARSE) {
        u32 cnt = lhist[tid];
        int idx = c0 * FINE_PER_COARSE + tid;
        if (cnt && idx < NFINE)
            gbase[tid] = (u32)atomicAdd((u32*)&fine_cursor[idx], cnt);
    }
    __syncthreads();
    #pragma unroll
    for (int k = 0; k < IPT; ++k) {
        int i = start + k * BLOCK + tid;
        if (i < EE) buf2[gbase[key[k]] + rank[k]] = item[k];
    }
}

// ---------------- PB: sort each fine bucket by node, emit CSR ----------------
// ssrc u32 = src(18) | dep<<18 (3)
__global__ __launch_bounds__(BLOCK) void pb_sort(const u32* __restrict__ buf2,
                                                 const int* __restrict__ fine_base,
                                                 int* __restrict__ ptr,
                                                 u32* __restrict__ ssrc) {
    __shared__ u32 nhist[NODES_PER_FINE];
    __shared__ u32 nbase[NODES_PER_FINE];
    __shared__ u32 lout[TILE];
    int tid = threadIdx.x;
    int b = blockIdx.x;
    int lo = fine_base[b];
    int hi = fine_base[b + 1];
    int cnt = hi - lo;
    if (tid < NODES_PER_FINE) nhist[tid] = 0;
    __syncthreads();

    u32 item[IPT]; u32 ln[IPT]; u32 rank[IPT];
    #pragma unroll
    for (int k = 0; k < IPT; ++k) {
        int i = lo + k * BLOCK + tid;
        if (i < hi) {
            u32 w = buf2[i];
            u32 l = w & 63u;
            ln[k]   = l;
            item[k] = w >> 6;                 // src | dep<<18
            rank[k] = atomicAdd(&nhist[l], 1u);
        }
    }
    __syncthreads();
    if (tid < NODES_PER_FINE) {
        u32 v = nhist[tid];
        u32 incl = v;
        #pragma unroll
        for (int off = 1; off < 64; off <<= 1) {
            u32 t = __shfl_up((int)incl, off, 64);
            if ((tid & 63) >= off) incl += t;
        }
        nbase[tid] = incl - v;                // exclusive
        ptr[b * NODES_PER_FINE + tid] = lo + (int)(incl - v);
    }
    __syncthreads();
    #pragma unroll
    for (int k = 0; k < IPT; ++k) {
        int i = lo + k * BLOCK + tid;
        if (i < hi) lout[nbase[ln[k]] + rank[k]] = item[k];
    }
    __syncthreads();
    for (int j = tid; j < cnt; j += BLOCK) ssrc[lo + j] = lout[j];
}

// ---------------- fused GRU iteration ----------------

__device__ __forceinline__ void acc_row20(float* x, const float* row) {
    const float4* v = (const float4*)row;
    float4 a0 = v[0], a1 = v[1], a2 = v[2], a3 = v[3], a4 = v[4];
    x[0]+=a0.x; x[1]+=a0.y; x[2]+=a0.z; x[3]+=a0.w;
    x[4]+=a1.x; x[5]+=a1.y; x[6]+=a1.z; x[7]+=a1.w;
    x[8]+=a2.x; x[9]+=a2.y; x[10]+=a2.z; x[11]+=a2.w;
    x[12]+=a3.x; x[13]+=a3.y; x[14]+=a3.z; x[15]+=a3.w;
    x[16]+=a4.x; x[17]+=a4.y; x[18]+=a4.z; x[19]+=a4.w;
}

__device__ __forceinline__ void load_row20(float* a, const float* row) {
    const float4* v = (const float4*)row;
    float4 a0 = v[0], a1 = v[1], a2 = v[2], a3 = v[3], a4 = v[4];
    a[0]=a0.x; a[1]=a0.y; a[2]=a0.z; a[3]=a0.w;
    a[4]=a1.x; a[5]=a1.y; a[6]=a1.z; a[7]=a1.w;
    a[8]=a2.x; a[9]=a2.y; a[10]=a2.z; a[11]=a2.w;
    a[12]=a3.x; a[13]=a3.y; a[14]=a3.z; a[15]=a3.w;
    a[16]=a4.x; a[17]=a4.y; a[18]=a4.z; a[19]=a4.w;
}

__device__ __forceinline__ void store_row20(float* row, const float* o) {
    float4* v = (float4*)row;
    v[0] = make_float4(o[0],  o[1],  o[2],  o[3]);
    v[1] = make_float4(o[4],  o[5],  o[6],  o[7]);
    v[2] = make_float4(o[8],  o[9],  o[10], o[11]);
    v[3] = make_float4(o[12], o[13], o[14], o[15]);
    v[4] = make_float4(o[16], o[17], o[18], o[19]);
}

__device__ __forceinline__ float fast_sigmoid(float t) {
    return 1.0f / (1.0f + __expf(-t));
}

__device__ __forceinline__ float fast_tanh(float t) {
    t = fminf(fmaxf(t, -15.0f), 15.0f);
    float e2 = __expf(2.0f * t);
    return (e2 - 1.0f) / (e2 + 1.0f);
}

__global__ __launch_bounds__(BLOCK) void gru_kernel(
    const float* __restrict__ h_in, float* __restrict__ h_out,
    const int* __restrict__ depth, const int* __restrict__ ptr,
    const u32* __restrict__ ssrc,
    const float* __restrict__ Wz, const float* __restrict__ bWz,
    const float* __restrict__ Uz, const float* __restrict__ bUz,
    const float* __restrict__ Wr, const float* __restrict__ bWr,
    const float* __restrict__ Ur, const float* __restrict__ bUr,
    const float* __restrict__ Wh, const float* __restrict__ bWh,
    const float* __restrict__ Uh, const float* __restrict__ bUh,
    int it, int isFinal)
{
    int u = blockIdx.x * BLOCK + threadIdx.x;
    if (u >= NN) return;

    bool act = (depth[u] + it) <= ITERS;
    if (!act) {
        float4* o = (float4*)(h_out + (size_t)u * DIM);
        if (isFinal) {
            float4 z4 = make_float4(0.f, 0.f, 0.f, 0.f);
            #pragma unroll
            for (int q = 0; q < 5; ++q) o[q] = z4;
        } else {
            const float4* hi = (const float4*)(h_in + (size_t)u * DIM);
            #pragma unroll
            for (int q = 0; q < 5; ++q) o[q] = hi[q];
        }
        return;
    }

    float x[DIM];
    #pragma unroll
    for (int k = 0; k < DIM; ++k) x[k] = 0.0f;

    int p = ptr[u];
    int dcnt = ptr[u + 1] - p;
    u32 lim = (u32)(ITERS - it);               // active src iff dep <= lim

    int e = 0;
    for (; e + 1 < dcnt; e += 2) {
        u32 w0 = ssrc[p + e], w1 = ssrc[p + e + 1];
        const float* r0 = h_in + (size_t)(w0 & 0x3FFFFu) * DIM;
        const float* r1 = h_in + (size_t)(w1 & 0x3FFFFu) * DIM;
        if ((w0 >> 18) <= lim) acc_row20(x, r0);
        if ((w1 >> 18) <= lim) acc_row20(x, r1);
    }
    if (e < dcnt) {
        u32 w0 = ssrc[p + e];
        if ((w0 >> 18) <= lim) acc_row20(x, h_in + (size_t)(w0 & 0x3FFFFu) * DIM);
    }

    float h[DIM];
    load_row20(h, h_in + (size_t)u * DIM);

    float z[DIM], rh[DIM];
    #pragma unroll
    for (int j = 0; j < DIM; ++j) {
        float sz = bWz[j] + bUz[j];
        float sr = bWr[j] + bUr[j];
        #pragma unroll
        for (int k = 0; k < DIM; ++k) {
            sz += x[k] * Wz[j * DIM + k];
            sz += h[k] * Uz[j * DIM + k];
            sr += x[k] * Wr[j * DIM + k];
            sr += h[k] * Ur[j * DIM + k];
        }
        z[j]  = fast_sigmoid(sz);
        rh[j] = fast_sigmoid(sr) * h[j];
    }

    float o[DIM];
    #pragma unroll
    for (int j = 0; j < DIM; ++j) {
        float sh = bWh[j] + bUh[j];
        #pragma unroll
        for (int k = 0; k < DIM; ++k) {
            sh += x[k]  * Wh[j * DIM + k];
            sh += rh[k] * Uh[j * DIM + k];
        }
        float hc = fast_tanh(sh);
        o[j] = z[j] * h[j] + (1.0f - z[j]) * hc;
    }

    store_row20(h_out + (size_t)u * DIM, o);
}

// ---------------- launch ----------------

extern "C" void kernel_launch(void* const* d_in, const int* in_sizes, int n_in,
                              void* d_out, int out_size, void* d_ws, size_t ws_size,
                              hipStream_t stream) {
    const float* h0    = (const float*)d_in[0];
    const int*   depth = (const int*)d_in[1];
    const int*   esrc  = (const int*)d_in[2];
    const int*   edst  = (const int*)d_in[3];
    const float* Wz  = (const float*)d_in[4];  const float* bWz = (const float*)d_in[5];
    const float* Uz  = (const float*)d_in[6];  const float* bUz = (const float*)d_in[7];
    const float* Wr  = (const float*)d_in[8];  const float* bWr = (const float*)d_in[9];
    const float* Ur  = (const float*)d_in[10]; const float* bUr = (const float*)d_in[11];
    const float* Wh  = (const float*)d_in[12]; const float* bWh = (const float*)d_in[13];
    const float* Uh  = (const float*)d_in[14]; const float* bUh = (const float*)d_in[15];
    float* out = (float*)d_out;

    // workspace layout (int32 index units)
    int* W = (int*)d_ws;
    int*  fine_cnt      = W + 0;                  // 3125
    int*  fine_base     = W + 3200;               // 3126
    int*  fine_cursor   = W + 6400;               // 3125
    int*  coarse_base   = W + 9600;               // 99
    int*  coarse_cursor = W + 9728;               // 98
    int*  ptr           = W + 9856;               // NN+1 = 200001
    u32*  buf1          = (u32*)(W + 212992);     // EE  (16B-aligned offset)
    u32*  buf2          = (u32*)(W + 212992 + EE);// EE
    float* h1           = (float*)(W + 212992 + 2 * EE); // NN*DIM
    u32*  ssrc          = buf1;                   // alias: buf1 dead after P2
    float* h2           = (float*)buf2;           // alias: buf2 dead after PB

    hipMemsetAsync(fine_cnt, 0, NFINE * sizeof(int), stream);

    int ngrid = (NN + BLOCK - 1) / BLOCK;
    int ntile = (EE + TILE - 1) / TILE;           // 1563

    k1_count<<<256, BLOCK, 0, stream>>>(edst, fine_cnt);
    k2_scan <<<1,   BLOCK, 0, stream>>>(fine_cnt, fine_base, fine_cursor,
                                        coarse_base, coarse_cursor, ptr);
    p1_split<<<ntile, BLOCK, 0, stream>>>(esrc, edst, depth, coarse_cursor, buf1);
    p2_split<<<ntile, BLOCK, 0, stream>>>(buf1, coarse_base, fine_cursor, buf2);
    pb_sort <<<NFINE, BLOCK, 0, stream>>>(buf2, fine_base, ptr, ssrc);

    gru_kernel<<<ngrid, BLOCK, 0, stream>>>(h0, h1, depth, ptr, ssrc,
        Wz, bWz, Uz, bUz, Wr, bWr, Ur, bUr, Wh, bWh, Uh, bUh, 0, 0);
    gru_kernel<<<ngrid, BLOCK, 0, stream>>>(h1, h2, depth, ptr, ssrc,
        Wz, bWz, Uz, bUz, Wr, bWr, Ur, bUr, Wh, bWh, Uh, bUh, 1, 0);
    gru_kernel<<<ngrid, BLOCK, 0, stream>>>(h2, out, depth, ptr, ssrc,
        Wz, bWz, Uz, bUz, Wr, bWr, Ur, bUr, Wh, bWh, Uh, bUh, 2, 1);
}